// Round 1
// baseline (456.261 us; speedup 1.0000x reference)
//
#include <hip/hip_runtime.h>
#include <math.h>

#define EPS 1e-5f
#define NROWS 1000000
#define C 64
#define B 8
#define CTX 256

// ---------------------------------------------------------------------------
// Kernel 1: h = silu(dataset_token) @ W^T + b
//   dataset_token: (B=8, CTX=256)  W: (2C=128, CTX=256)  b: (128,)
//   ws[0    .. 511] = shift  (h[:, :64], layout [j*64 + c])
//   ws[512  ..1023] = 1+scale (h[:, 64:], layout [j*64 + c])
// One block, 1024 threads, one output element each (256 MACs).
// ---------------------------------------------------------------------------
__global__ __launch_bounds__(1024) void token_gemm(
        const float* __restrict__ dt, const float* __restrict__ W,
        const float* __restrict__ bias, float* __restrict__ ws) {
    __shared__ float sdt[B * CTX];          // 8 KB: silu(dataset_token)
    int t = threadIdx.x;                    // 0..1023
    for (int i = t; i < B * CTX; i += 1024) {
        float v = dt[i];
        sdt[i] = v / (1.0f + expf(-v));     // silu
    }
    __syncthreads();

    int j = t >> 7;                         // 0..7   (batch row)
    int k = t & 127;                        // 0..127 (output feature)
    const float* __restrict__ wrow = W + k * CTX;
    const float* __restrict__ drow = sdt + j * CTX;   // wave-uniform -> LDS broadcast
    float acc = 0.0f;
    #pragma unroll 8
    for (int i = 0; i < CTX; ++i) acc += wrow[i] * drow[i];
    acc += bias[k];

    if (k < C) ws[j * C + k] = acc;                       // shift
    else       ws[512 + j * C + (k - C)] = 1.0f + acc;    // 1 + scale
}

// ---------------------------------------------------------------------------
// Kernel 2: per-row LayerNorm + FiLM modulation.
//   16 lanes per row, one float4 per lane (C=64). 256 threads -> 16 rows/block.
// ---------------------------------------------------------------------------
__global__ __launch_bounds__(256) void ln_mod(
        const float* __restrict__ x, const float* __restrict__ gamma,
        const float* __restrict__ beta, const int* __restrict__ coors,
        const float* __restrict__ h, float* __restrict__ out, int n) {
    __shared__ float sh[1024];              // [0..511]=shift, [512..1023]=1+scale
    int t = threadIdx.x;
    ((float4*)sh)[t] = ((const float4*)h)[t];   // 256 * 16B = 4 KB stage
    __syncthreads();

    int group = t >> 4;                     // 0..15  (row within block)
    int lane  = t & 15;                     // 0..15  (float4 within row)
    int row = blockIdx.x * 16 + group;
    if (row >= n) return;

    float4 v = ((const float4*)x)[row * 16 + lane];

    float s  = v.x + v.y + v.z + v.w;
    float ss = v.x * v.x + v.y * v.y + v.z * v.z + v.w * v.w;
    // butterfly reduce across the 16 lanes of this row
    #pragma unroll
    for (int m = 1; m < 16; m <<= 1) {
        s  += __shfl_xor(s,  m, 16);
        ss += __shfl_xor(ss, m, 16);
    }
    float mu   = s * (1.0f / 64.0f);
    float var  = ss * (1.0f / 64.0f) - mu * mu;
    float rstd = rsqrtf(var + EPS);

    int bidx = coors[row * 4];              // batch index (column 0 of coors)

    float4 g  = ((const float4*)gamma)[lane];
    float4 be = ((const float4*)beta)[lane];
    float4 sc = ((const float4*)(sh + 512 + bidx * C))[lane];  // 1+scale
    float4 sf = ((const float4*)(sh + bidx * C))[lane];        // shift

    float4 o;
    o.x = ((v.x - mu) * rstd * g.x + be.x) * sc.x + sf.x;
    o.y = ((v.y - mu) * rstd * g.y + be.y) * sc.y + sf.y;
    o.z = ((v.z - mu) * rstd * g.z + be.z) * sc.z + sf.z;
    o.w = ((v.w - mu) * rstd * g.w + be.w) * sc.w + sf.w;

    ((float4*)out)[row * 16 + lane] = o;
}

extern "C" void kernel_launch(void* const* d_in, const int* in_sizes, int n_in,
                              void* d_out, int out_size, void* d_ws, size_t ws_size,
                              hipStream_t stream) {
    const float* x     = (const float*)d_in[0];  // (N, 64)
    const float* dt    = (const float*)d_in[1];  // (8, 256)
    const float* gamma = (const float*)d_in[2];  // (64,)
    const float* beta  = (const float*)d_in[3];  // (64,)
    const float* W     = (const float*)d_in[4];  // (128, 256)
    const float* bias  = (const float*)d_in[5];  // (128,)
    const int*   coors = (const int*)d_in[6];    // (N, 4) int32
    float* out = (float*)d_out;
    float* ws  = (float*)d_ws;                   // 1024 floats used

    token_gemm<<<1, 1024, 0, stream>>>(dt, W, bias, ws);

    int nblocks = (NROWS + 15) / 16;             // 62500
    ln_mod<<<nblocks, 256, 0, stream>>>(x, gamma, beta, coors, ws, out, NROWS);
}